// Round 2
// baseline (3094.067 us; speedup 1.0000x reference)
//
#include <hip/hip_runtime.h>
#include <math.h>

// Net_8074538517117: bipartite GNN forward.
// Decomposition: per-edge MLP feats=[x_dst|x_src|et] @ W1 -> split W1 into
// node-side projections A=x@W1a+b1 (dst part), B=x@W1b (src part); edge kernel
// does relu(A[dst]+B[src]+et@W1c) and atomically accumulates into S[dst] plus
// a count. Since @W2 is linear, segment_sum(relu(h)@W2+b2) = S@W2 + cnt*b2,
// computed node-side. This removes both 64x64 GEMMs from the 800k-edge loop.

#define N_VARN 50000
#define N_CONN 50000
#define NNODES 100000
#define NEDGES 800000

// ---------------- embed: per-node 2->64 relu ->64 MLP, scatter to x0 --------
__global__ __launch_bounds__(256) void embed_kernel(
    const float* __restrict__ vf, const float* __restrict__ cf,
    const float* __restrict__ vw1, const float* __restrict__ vb1,
    const float* __restrict__ vw2, const float* __restrict__ vb2,
    const float* __restrict__ cw1, const float* __restrict__ cb1,
    const float* __restrict__ cw2, const float* __restrict__ cb2,
    const int* __restrict__ av, const int* __restrict__ ac,
    float* __restrict__ x0) {
  int node = blockIdx.x * 4 + (threadIdx.x >> 6);
  int lane = threadIdx.x & 63;
  const float* in;
  const float *w1, *b1, *w2, *b2;
  int row;
  if (node < N_VARN) {
    in = vf + node * 2; w1 = vw1; b1 = vb1; w2 = vw2; b2 = vb2; row = av[node];
  } else {
    int i = node - N_VARN;
    in = cf + i * 2; w1 = cw1; b1 = cb1; w2 = cw2; b2 = cb2; row = ac[i];
  }
  float i0 = in[0], i1 = in[1];
  float h = fmaxf(fmaf(i0, w1[lane], fmaf(i1, w1[64 + lane], b1[lane])), 0.f);
  float acc = b2[lane];
#pragma unroll
  for (int k = 0; k < 64; ++k) acc = fmaf(__shfl(h, k), w2[k * 64 + lane], acc);
  x0[row * 64 + lane] = acc;
}

// ---------------- proj: A = x@W1[0:64] + b1 ; B = x@W1[64:128] --------------
__global__ __launch_bounds__(256) void proj_kernel(
    const float* __restrict__ x, const float* __restrict__ w1,
    const float* __restrict__ b1,
    float* __restrict__ A, float* __restrict__ B) {
  int node = blockIdx.x * 4 + (threadIdx.x >> 6);
  int lane = threadIdx.x & 63;
  float xv = x[node * 64 + lane];
  float a = b1[lane];
  float b = 0.f;
#pragma unroll
  for (int k = 0; k < 64; ++k) {
    float xk = __shfl(xv, k);
    a = fmaf(xk, w1[k * 64 + lane], a);
    b = fmaf(xk, w1[(64 + k) * 64 + lane], b);
  }
  A[node * 64 + lane] = a;
  B[node * 64 + lane] = b;
}

// ---------------- edge: scatter relu(A[dst]+B[src]+et@W1c) into S[dst] ------
__global__ __launch_bounds__(256) void edge_kernel(
    const int* __restrict__ ei, const float* __restrict__ et,
    const float* __restrict__ A, const float* __restrict__ B,
    const float* __restrict__ w1c,  // rows 128..129 of W1 (2 x 64)
    float* __restrict__ S, float* __restrict__ cnt) {
  int t = blockIdx.x * blockDim.x + threadIdx.x;  // NEDGES*16 threads
  int e = t >> 4;
  int q = t & 15;
  if (e >= NEDGES) return;
  int src = ei[e];
  int dst = ei[NEDGES + e];
  float et0 = et[e * 2 + 0];
  float et1 = et[e * 2 + 1];
  const float4 a = *(const float4*)(A + dst * 64 + q * 4);
  const float4 b = *(const float4*)(B + src * 64 + q * 4);
  const float4 c0 = *(const float4*)(w1c + q * 4);
  const float4 c1 = *(const float4*)(w1c + 64 + q * 4);
  float h0 = fmaxf(a.x + b.x + fmaf(et0, c0.x, et1 * c1.x), 0.f);
  float h1 = fmaxf(a.y + b.y + fmaf(et0, c0.y, et1 * c1.y), 0.f);
  float h2 = fmaxf(a.z + b.z + fmaf(et0, c0.z, et1 * c1.z), 0.f);
  float h3 = fmaxf(a.w + b.w + fmaf(et0, c0.w, et1 * c1.w), 0.f);
  float* s = S + dst * 64 + q * 4;
  unsafeAtomicAdd(s + 0, h0);
  unsafeAtomicAdd(s + 1, h1);
  unsafeAtomicAdd(s + 2, h2);
  unsafeAtomicAdd(s + 3, h3);
  if (q == 0) unsafeAtomicAdd(cnt + dst, 1.0f);
}

// ---------------- finalize: x_out = relu((S@W2 + cnt*b2)/max(cnt,1)) --------
__global__ __launch_bounds__(256) void final_kernel(
    const float* __restrict__ S, const float* __restrict__ cnt,
    const float* __restrict__ w2, const float* __restrict__ b2,
    float* __restrict__ xout) {
  int node = blockIdx.x * 4 + (threadIdx.x >> 6);
  int lane = threadIdx.x & 63;
  float sv = S[node * 64 + lane];
  float c = cnt[node];
  float acc = c * b2[lane];
#pragma unroll
  for (int k = 0; k < 64; ++k) acc = fmaf(__shfl(sv, k), w2[k * 64 + lane], acc);
  float m = fmaxf(c, 1.0f);
  xout[node * 64 + lane] = fmaxf(acc / m, 0.f);
}

// ---------------- head: concat(x0..x3)[var] -> fc1 relu fc2 relu fc3 sigmoid
__global__ __launch_bounds__(256) void head_kernel(
    const float* __restrict__ x0, const float* __restrict__ x1,
    const float* __restrict__ x2, const float* __restrict__ x3,
    const int* __restrict__ av,
    const float* __restrict__ fc1w, const float* __restrict__ fc1b,
    const float* __restrict__ fc2w, const float* __restrict__ fc2b,
    const float* __restrict__ fc3w, const float* __restrict__ fc3b,
    float* __restrict__ out) {
  int node = blockIdx.x * 4 + (threadIdx.x >> 6);
  int lane = threadIdx.x & 63;
  int row = av[node];
  float r0 = x0[row * 64 + lane];
  float r1 = x1[row * 64 + lane];
  float r2 = x2[row * 64 + lane];
  float r3 = x3[row * 64 + lane];
  float acc = fc1b[lane];
#pragma unroll
  for (int k = 0; k < 64; ++k) {
    acc = fmaf(__shfl(r0, k), fc1w[k * 64 + lane], acc);
    acc = fmaf(__shfl(r1, k), fc1w[(64 + k) * 64 + lane], acc);
    acc = fmaf(__shfl(r2, k), fc1w[(128 + k) * 64 + lane], acc);
    acc = fmaf(__shfl(r3, k), fc1w[(192 + k) * 64 + lane], acc);
  }
  float h1 = fmaxf(acc, 0.f);
  float acc2 = fc2b[lane];
#pragma unroll
  for (int k = 0; k < 64; ++k)
    acc2 = fmaf(__shfl(h1, k), fc2w[k * 64 + lane], acc2);
  float h2 = fmaxf(acc2, 0.f);
  float p = h2 * fc3w[lane];
#pragma unroll
  for (int off = 32; off; off >>= 1) p += __shfl_down(p, off);
  if (lane == 0) {
    float z = p + fc3b[0];
    out[node] = 1.f / (1.f + expf(-z));
  }
}

extern "C" void kernel_launch(void* const* d_in, const int* in_sizes, int n_in,
                              void* d_out, int out_size, void* d_ws,
                              size_t ws_size, hipStream_t stream) {
  const float* vf = (const float*)d_in[0];
  const float* cf = (const float*)d_in[1];
  const int* ei = (const int*)d_in[2];
  const float* et = (const float*)d_in[3];
  const int* av = (const int*)d_in[4];
  const int* ac = (const int*)d_in[5];
  // d_in[6] = num_nodes (scalar, known constant 100000)
  const float* vw1 = (const float*)d_in[7];
  const float* vb1 = (const float*)d_in[8];
  const float* vw2 = (const float*)d_in[9];
  const float* vb2 = (const float*)d_in[10];
  const float* cw1 = (const float*)d_in[11];
  const float* cb1 = (const float*)d_in[12];
  const float* cw2 = (const float*)d_in[13];
  const float* cb2 = (const float*)d_in[14];
  const float* convw1[3] = {(const float*)d_in[15], (const float*)d_in[19],
                            (const float*)d_in[23]};
  const float* convb1[3] = {(const float*)d_in[16], (const float*)d_in[20],
                            (const float*)d_in[24]};
  const float* convw2[3] = {(const float*)d_in[17], (const float*)d_in[21],
                            (const float*)d_in[25]};
  const float* convb2[3] = {(const float*)d_in[18], (const float*)d_in[22],
                            (const float*)d_in[26]};
  const float* fc1w = (const float*)d_in[27];
  const float* fc1b = (const float*)d_in[28];
  const float* fc2w = (const float*)d_in[29];
  const float* fc2b = (const float*)d_in[30];
  const float* fc3w = (const float*)d_in[31];
  const float* fc3b = (const float*)d_in[32];

  // workspace layout (floats)
  float* ws = (float*)d_ws;
  const size_t ROW = (size_t)NNODES * 64;
  float* x[4];
  x[0] = ws;
  x[1] = ws + ROW;
  x[2] = ws + 2 * ROW;
  x[3] = ws + 3 * ROW;
  float* A = ws + 4 * ROW;
  float* B = ws + 5 * ROW;
  float* S = ws + 6 * ROW;
  float* cnt = ws + 7 * ROW;  // NNODES floats

  embed_kernel<<<NNODES / 4, 256, 0, stream>>>(vf, cf, vw1, vb1, vw2, vb2, cw1,
                                               cb1, cw2, cb2, av, ac, x[0]);

  for (int c = 0; c < 3; ++c) {
    proj_kernel<<<NNODES / 4, 256, 0, stream>>>(x[c], convw1[c], convb1[c], A,
                                                B);
    hipMemsetAsync(S, 0, ROW * sizeof(float), stream);
    hipMemsetAsync(cnt, 0, NNODES * sizeof(float), stream);
    edge_kernel<<<NEDGES * 16 / 256, 256, 0, stream>>>(
        ei, et, A, B, convw1[c] + 128 * 64, S, cnt);
    final_kernel<<<NNODES / 4, 256, 0, stream>>>(S, cnt, convw2[c], convb2[c],
                                                 x[c + 1]);
  }

  head_kernel<<<N_VARN / 4, 256, 0, stream>>>(x[0], x[1], x[2], x[3], av, fc1w,
                                              fc1b, fc2w, fc2b, fc3w, fc3b,
                                              (float*)d_out);
}

// Round 3
// 1097.512 us; speedup vs baseline: 2.8192x; 2.8192x over previous
//
#include <hip/hip_runtime.h>
#include <math.h>

// Net_8074538517117: bipartite GNN forward, CSR-based (no feature atomics).
// Per-edge MLP decomposition (round 2, verified): feats@W1 = A[dst]+B[src]+et@W1c
// with A=x@W1[0:64]+b1, B=x@W1[64:128]; and segsum(relu(h)@W2+b2) =
// (segsum relu(h))@W2 + cnt*b2. Round 3: build dst-CSR once per launch
// (hist -> scan -> scatter), then each conv is a gather-only wave-per-node
// kernel with the W2 GEMM + mean + relu fused in the epilogue.

#define N_VARN 50000
#define NNODES 100000
#define NEDGES 800000
#define NB_SCAN 196  // ceil(100000/512)

// ---------------- embed: per-node 2->64 relu ->64 MLP, scatter to x0 --------
__global__ __launch_bounds__(256) void embed_kernel(
    const float* __restrict__ vf, const float* __restrict__ cf,
    const float* __restrict__ vw1, const float* __restrict__ vb1,
    const float* __restrict__ vw2, const float* __restrict__ vb2,
    const float* __restrict__ cw1, const float* __restrict__ cb1,
    const float* __restrict__ cw2, const float* __restrict__ cb2,
    const int* __restrict__ av, const int* __restrict__ ac,
    float* __restrict__ x0) {
  int node = blockIdx.x * 4 + (threadIdx.x >> 6);
  int lane = threadIdx.x & 63;
  const float* in;
  const float *w1, *b1, *w2, *b2;
  int row;
  if (node < N_VARN) {
    in = vf + node * 2; w1 = vw1; b1 = vb1; w2 = vw2; b2 = vb2; row = av[node];
  } else {
    int i = node - N_VARN;
    in = cf + i * 2; w1 = cw1; b1 = cb1; w2 = cw2; b2 = cb2; row = ac[i];
  }
  float i0 = in[0], i1 = in[1];
  float h = fmaxf(fmaf(i0, w1[lane], fmaf(i1, w1[64 + lane], b1[lane])), 0.f);
  float acc = b2[lane];
#pragma unroll
  for (int k = 0; k < 64; ++k) acc = fmaf(__shfl(h, k), w2[k * 64 + lane], acc);
  x0[row * 64 + lane] = acc;
}

// ---------------- CSR build ----------------
__global__ __launch_bounds__(256) void hist_kernel(const int* __restrict__ ei,
                                                   unsigned* __restrict__ deg) {
  int e = blockIdx.x * 256 + threadIdx.x;  // grid covers NEDGES exactly
  atomicAdd(&deg[ei[NEDGES + e]], 1u);
}

__global__ __launch_bounds__(512) void scan1_kernel(
    const unsigned* __restrict__ deg, unsigned* __restrict__ blocksum) {
  __shared__ unsigned sm[512];
  int t = threadIdx.x;
  int i = blockIdx.x * 512 + t;
  sm[t] = (i < NNODES) ? deg[i] : 0u;
  __syncthreads();
  for (int off = 256; off > 0; off >>= 1) {
    if (t < off) sm[t] += sm[t + off];
    __syncthreads();
  }
  if (t == 0) blocksum[blockIdx.x] = sm[0];
}

__global__ __launch_bounds__(256) void scan2_kernel(
    const unsigned* __restrict__ blocksum, unsigned* __restrict__ blockoff) {
  __shared__ unsigned sm[256];
  int t = threadIdx.x;
  sm[t] = (t < NB_SCAN) ? blocksum[t] : 0u;
  __syncthreads();
  if (t == 0) {
    unsigned run = 0;
    for (int j = 0; j < NB_SCAN; ++j) {
      unsigned v = sm[j];
      sm[j] = run;
      run += v;
    }
  }
  __syncthreads();
  if (t < NB_SCAN) blockoff[t] = sm[t];
}

__global__ __launch_bounds__(512) void scan3_kernel(
    const unsigned* __restrict__ deg, const unsigned* __restrict__ blockoff,
    unsigned* __restrict__ rowptr) {
  __shared__ unsigned sm[512];
  int t = threadIdx.x;
  int i = blockIdx.x * 512 + t;
  unsigned v = (i < NNODES) ? deg[i] : 0u;
  sm[t] = v;
  __syncthreads();
  for (int off = 1; off < 512; off <<= 1) {
    unsigned add = (t >= off) ? sm[t - off] : 0u;
    __syncthreads();
    sm[t] += add;
    __syncthreads();
  }
  if (i <= NNODES) rowptr[i] = blockoff[blockIdx.x] + sm[t] - v;  // exclusive
}

__global__ __launch_bounds__(256) void scatter_kernel(
    const int* __restrict__ ei, const float* __restrict__ et,
    const unsigned* __restrict__ rowptr, unsigned* __restrict__ cursor,
    int* __restrict__ colsrc, float2* __restrict__ colet) {
  int e = blockIdx.x * 256 + threadIdx.x;  // grid covers NEDGES exactly
  int d = ei[NEDGES + e];
  unsigned pos = rowptr[d] + atomicAdd(&cursor[d], 1u);
  colsrc[pos] = ei[e];
  colet[pos] = ((const float2*)et)[e];
}

// ---------------- proj: A = x@W1[0:64] + b1 ; B = x@W1[64:128] --------------
__global__ __launch_bounds__(256) void proj_kernel(
    const float* __restrict__ x, const float* __restrict__ w1,
    const float* __restrict__ b1,
    float* __restrict__ A, float* __restrict__ B) {
  int node = blockIdx.x * 4 + (threadIdx.x >> 6);
  int lane = threadIdx.x & 63;
  float xv = x[node * 64 + lane];
  float a = b1[lane];
  float b = 0.f;
#pragma unroll
  for (int k = 0; k < 64; ++k) {
    float xk = __shfl(xv, k);
    a = fmaf(xk, w1[k * 64 + lane], a);
    b = fmaf(xk, w1[(64 + k) * 64 + lane], b);
  }
  A[node * 64 + lane] = a;
  B[node * 64 + lane] = b;
}

// ------- aggregate: acc = sum_e relu(A[n]+B[src]+et@W1c); fused W2+mean+relu
__global__ __launch_bounds__(256) void agg_kernel(
    const unsigned* __restrict__ rowptr, const int* __restrict__ colsrc,
    const float2* __restrict__ colet, const float* __restrict__ A,
    const float* __restrict__ B, const float* __restrict__ w1c,
    const float* __restrict__ w2, const float* __restrict__ b2,
    float* __restrict__ xout) {
  int node = blockIdx.x * 4 + (threadIdx.x >> 6);
  int lane = threadIdx.x & 63;
  unsigned beg = rowptr[node], end = rowptr[node + 1];
  float a = A[node * 64 + lane];
  float c0 = w1c[lane], c1 = w1c[64 + lane];
  float acc = 0.f;
  for (unsigned i = beg; i < end; ++i) {
    int s = colsrc[i];
    float2 t = colet[i];
    float h = a + B[s * 64 + lane] + fmaf(t.x, c0, t.y * c1);
    acc += fmaxf(h, 0.f);
  }
  float cntf = (float)(end - beg);
  float o = cntf * b2[lane];
#pragma unroll
  for (int k = 0; k < 64; ++k) o = fmaf(__shfl(acc, k), w2[k * 64 + lane], o);
  o /= fmaxf(cntf, 1.f);
  xout[node * 64 + lane] = fmaxf(o, 0.f);
}

// ---------------- head: concat(x0..x3)[var] -> fc1 relu fc2 relu fc3 sigmoid
__global__ __launch_bounds__(256) void head_kernel(
    const float* __restrict__ x0, const float* __restrict__ x1,
    const float* __restrict__ x2, const float* __restrict__ x3,
    const int* __restrict__ av,
    const float* __restrict__ fc1w, const float* __restrict__ fc1b,
    const float* __restrict__ fc2w, const float* __restrict__ fc2b,
    const float* __restrict__ fc3w, const float* __restrict__ fc3b,
    float* __restrict__ out) {
  int node = blockIdx.x * 4 + (threadIdx.x >> 6);
  int lane = threadIdx.x & 63;
  int row = av[node];
  float r0 = x0[row * 64 + lane];
  float r1 = x1[row * 64 + lane];
  float r2 = x2[row * 64 + lane];
  float r3 = x3[row * 64 + lane];
  float acc = fc1b[lane];
#pragma unroll
  for (int k = 0; k < 64; ++k) {
    acc = fmaf(__shfl(r0, k), fc1w[k * 64 + lane], acc);
    acc = fmaf(__shfl(r1, k), fc1w[(64 + k) * 64 + lane], acc);
    acc = fmaf(__shfl(r2, k), fc1w[(128 + k) * 64 + lane], acc);
    acc = fmaf(__shfl(r3, k), fc1w[(192 + k) * 64 + lane], acc);
  }
  float h1 = fmaxf(acc, 0.f);
  float acc2 = fc2b[lane];
#pragma unroll
  for (int k = 0; k < 64; ++k)
    acc2 = fmaf(__shfl(h1, k), fc2w[k * 64 + lane], acc2);
  float h2 = fmaxf(acc2, 0.f);
  float p = h2 * fc3w[lane];
#pragma unroll
  for (int off = 32; off; off >>= 1) p += __shfl_down(p, off);
  if (lane == 0) {
    float z = p + fc3b[0];
    out[node] = 1.f / (1.f + expf(-z));
  }
}

extern "C" void kernel_launch(void* const* d_in, const int* in_sizes, int n_in,
                              void* d_out, int out_size, void* d_ws,
                              size_t ws_size, hipStream_t stream) {
  const float* vf = (const float*)d_in[0];
  const float* cf = (const float*)d_in[1];
  const int* ei = (const int*)d_in[2];
  const float* et = (const float*)d_in[3];
  const int* av = (const int*)d_in[4];
  const int* ac = (const int*)d_in[5];
  // d_in[6] = num_nodes (scalar, 100000)
  const float* vw1 = (const float*)d_in[7];
  const float* vb1 = (const float*)d_in[8];
  const float* vw2 = (const float*)d_in[9];
  const float* vb2 = (const float*)d_in[10];
  const float* cw1 = (const float*)d_in[11];
  const float* cb1 = (const float*)d_in[12];
  const float* cw2 = (const float*)d_in[13];
  const float* cb2 = (const float*)d_in[14];
  const float* convw1[3] = {(const float*)d_in[15], (const float*)d_in[19],
                            (const float*)d_in[23]};
  const float* convb1[3] = {(const float*)d_in[16], (const float*)d_in[20],
                            (const float*)d_in[24]};
  const float* convw2[3] = {(const float*)d_in[17], (const float*)d_in[21],
                            (const float*)d_in[25]};
  const float* convb2[3] = {(const float*)d_in[18], (const float*)d_in[22],
                            (const float*)d_in[26]};
  const float* fc1w = (const float*)d_in[27];
  const float* fc1b = (const float*)d_in[28];
  const float* fc2w = (const float*)d_in[29];
  const float* fc2b = (const float*)d_in[30];
  const float* fc3w = (const float*)d_in[31];
  const float* fc3b = (const float*)d_in[32];

  // workspace layout (float units)
  float* ws = (float*)d_ws;
  const size_t ROW = (size_t)NNODES * 64;
  float* x[4] = {ws, ws + ROW, ws + 2 * ROW, ws + 3 * ROW};
  float* A = ws + 4 * ROW;
  float* B = ws + 5 * ROW;
  float2* colet = (float2*)(ws + 6 * ROW);                 // NEDGES float2
  int* colsrc = (int*)(ws + 6 * ROW + 2 * (size_t)NEDGES); // NEDGES int
  unsigned* rowptr = (unsigned*)(colsrc + NEDGES);         // NNODES+1
  unsigned* deg = rowptr + NNODES + 1;                     // NNODES
  unsigned* cursor = deg + NNODES;                         // NNODES
  unsigned* blocksum = cursor + NNODES;                    // 256
  unsigned* blockoff = blocksum + 256;                     // 256

  embed_kernel<<<NNODES / 4, 256, 0, stream>>>(vf, cf, vw1, vb1, vw2, vb2, cw1,
                                               cb1, cw2, cb2, av, ac, x[0]);

  // CSR build (once; reused by all 3 convs)
  hipMemsetAsync(deg, 0, NNODES * sizeof(unsigned), stream);
  hipMemsetAsync(cursor, 0, NNODES * sizeof(unsigned), stream);
  hist_kernel<<<NEDGES / 256, 256, 0, stream>>>(ei, deg);
  scan1_kernel<<<NB_SCAN, 512, 0, stream>>>(deg, blocksum);
  scan2_kernel<<<1, 256, 0, stream>>>(blocksum, blockoff);
  scan3_kernel<<<NB_SCAN, 512, 0, stream>>>(deg, blockoff, rowptr);
  scatter_kernel<<<NEDGES / 256, 256, 0, stream>>>(ei, et, rowptr, cursor,
                                                   colsrc, colet);

  for (int c = 0; c < 3; ++c) {
    proj_kernel<<<NNODES / 4, 256, 0, stream>>>(x[c], convw1[c], convb1[c], A,
                                                B);
    agg_kernel<<<NNODES / 4, 256, 0, stream>>>(
        rowptr, colsrc, colet, A, B, convw1[c] + 128 * 64, convw2[c],
        convb2[c], x[c + 1]);
  }

  head_kernel<<<N_VARN / 4, 256, 0, stream>>>(x[0], x[1], x[2], x[3], av, fc1w,
                                              fc1b, fc2w, fc2b, fc3w, fc3b,
                                              (float*)d_out);
}